// Round 6
// baseline (1160.530 us; speedup 1.0000x reference)
//
#include <hip/hip_runtime.h>

// ERNN cell on MI355X. Inputs/outputs FLOAT32.
// P = I + V2@V  =>  E = P^2 - I = V2G @ V  (rank 64!),  V2G = V2@(2I + V@V2).
// wxp[t] = x[t]@(W@P) + b@P  precomputed in parallel (bf16, scan-ready layout).
// per step: s = h_cur + h_prev;  u = s@V2G;  pre = s + u@V + wxp[t]
//           h = a*(tanh(pre) - h_prev) + (1-a)*h_cur   (K iters, K=1)
// h stays f32 in registers; s (16x256) and u (16x64) round-trip LDS in bf16.
// Scan: 16 WGs x 512 threads; stage1 (s@V2G) on waves 0-3, stage2+epilogue on all.

#define HID   256
#define NF    128
#define SEQ   1024
#define SSTR  264    // s LDS row stride (bf16 elems, pad 8)
#define USTR  72     // u LDS row stride (bf16 elems, pad 8)

typedef __bf16 bf16_t;
typedef __bf16 bf16x8 __attribute__((ext_vector_type(8)));
typedef float  f32x4  __attribute__((ext_vector_type(4)));

__device__ __forceinline__ float fast_tanh(float x) {
    float e = __builtin_amdgcn_exp2f(x * 2.8853900817779268f);
    return 1.0f - 2.0f * __builtin_amdgcn_rcpf(e + 1.0f);
}

// ---------- P = V2@V + I (f32) ----------
__global__ void k_P(const float* __restrict__ V2, const float* __restrict__ V,
                    float* __restrict__ P) {
    __shared__ float v2row[64];
    int i = blockIdx.x, j = threadIdx.x;
    if (j < 64) v2row[j] = V2[i * 64 + j];
    __syncthreads();
    float s = (i == j) ? 1.0f : 0.0f;
    #pragma unroll 4
    for (int v = 0; v < 64; ++v) s += v2row[v] * V[v * HID + j];
    P[i * HID + j] = s;
}

// ---------- G = V@V2 + 2I (64x64 f32) ----------
__global__ void k_G(const float* __restrict__ V, const float* __restrict__ V2,
                    float* __restrict__ G) {
    __shared__ float vrow[HID];
    int i = blockIdx.x, j = threadIdx.x;       // 64 threads
    for (int k = j; k < HID; k += 64) vrow[k] = V[i * HID + k];
    __syncthreads();
    float s = (i == j) ? 2.0f : 0.0f;
    #pragma unroll 4
    for (int k = 0; k < HID; ++k) s += vrow[k] * V2[k * 64 + j];
    G[i * 64 + j] = s;
}

// ---------- V2G = bf16(V2@G) (256x64) ----------
__global__ void k_V2G(const float* __restrict__ V2, const float* __restrict__ G,
                      bf16_t* __restrict__ V2G) {
    __shared__ float v2row[64];
    int i = blockIdx.x, j = threadIdx.x;       // 64 threads
    v2row[j] = V2[i * 64 + j];
    __syncthreads();
    float s = 0.f;
    #pragma unroll 4
    for (int k = 0; k < 64; ++k) s += v2row[k] * G[k * 64 + j];
    V2G[i * 64 + j] = (bf16_t)s;
}

// ---------- Vb = bf16(V) (64x256) ----------
__global__ void k_Vb(const float* __restrict__ V, bf16_t* __restrict__ Vb) {
    int i = blockIdx.x, j = threadIdx.x;
    Vb[i * HID + j] = (bf16_t)V[i * HID + j];
}

// ---------- WP = bf16(W@P), bP = b@P (f32) ----------
__global__ void k_WP(const float* __restrict__ W, const float* __restrict__ b,
                     const float* __restrict__ P,
                     bf16_t* __restrict__ WP, float* __restrict__ bP) {
    __shared__ float row[HID];
    int i = blockIdx.x, j = threadIdx.x;
    if (i < NF) {
        row[j] = W[i * HID + j];
        __syncthreads();
        float s = 0.f;
        #pragma unroll 4
        for (int k = 0; k < HID; ++k) s += row[k] * P[k * HID + j];
        WP[i * HID + j] = (bf16_t)s;
    } else {
        row[j] = b[j];
        __syncthreads();
        float s = 0.f;
        #pragma unroll 4
        for (int k = 0; k < HID; ++k) s += row[k] * P[k * HID + j];
        bP[j] = s;
    }
}

// ---------- E = bf16(P@P - I) (fallback path only) ----------
__global__ void k_E(const float* __restrict__ P, bf16_t* __restrict__ E) {
    __shared__ float prow[HID];
    int i = blockIdx.x, j = threadIdx.x;
    prow[j] = P[i * HID + j];
    __syncthreads();
    float s = (i == j) ? -1.0f : 0.0f;
    #pragma unroll 4
    for (int k = 0; k < HID; ++k) s += prow[k] * P[k * HID + j];
    E[i * HID + j] = (bf16_t)s;
}

// ---------- wxp = bf16(x@WP + bP) in scan-ready layout ----------
__global__ __launch_bounds__(256) void k_wxp(const float* __restrict__ x,
                                             const bf16_t* __restrict__ WP,
                                             const float* __restrict__ bP,
                                             bf16_t* __restrict__ wxp) {
    int lane = threadIdx.x & 63, w = threadIdx.x >> 6;
    int quad = lane >> 4, m = lane & 15;
    bf16x8 Bf[4][4];
    float bPv[4];
    #pragma unroll
    for (int c = 0; c < 4; ++c) {
        int col = w * 64 + c * 16 + m;
        bPv[c] = bP[col];
        #pragma unroll
        for (int kt = 0; kt < 4; ++kt) {
            bf16x8 f;
            #pragma unroll
            for (int j = 0; j < 8; ++j)
                f[j] = WP[(kt * 32 + quad * 8 + j) * HID + col];
            Bf[c][kt] = f;
        }
    }
    for (int i = 0; i < 8; ++i) {
        int tile = blockIdx.x * 8 + i;          // t*16 + g
        int t = tile >> 4, g = tile & 15;
        const float* xp = x + (((t * 256) + g * 16 + m) * NF + quad * 8);
        f32x4 acc[4];
        #pragma unroll
        for (int c = 0; c < 4; ++c) acc[c] = (f32x4){bPv[c], bPv[c], bPv[c], bPv[c]};
        #pragma unroll
        for (int kt = 0; kt < 4; ++kt) {
            f32x4 xa = *(const f32x4*)(xp + kt * 32);
            f32x4 xb = *(const f32x4*)(xp + kt * 32 + 4);
            bf16x8 a;
            #pragma unroll
            for (int j = 0; j < 4; ++j) { a[j] = (bf16_t)xa[j]; a[4 + j] = (bf16_t)xb[j]; }
            #pragma unroll
            for (int c = 0; c < 4; ++c)
                acc[c] = __builtin_amdgcn_mfma_f32_16x16x32_bf16(a, Bf[c][kt], acc[c], 0, 0, 0);
        }
        bf16x8 lo, hi;
        #pragma unroll
        for (int c = 0; c < 2; ++c)
            #pragma unroll
            for (int r = 0; r < 4; ++r) {
                lo[c * 4 + r] = (bf16_t)acc[c][r];
                hi[c * 4 + r] = (bf16_t)acc[2 + c][r];
            }
        long tb = (long)tile * 512;
        *(bf16x8*)(wxp + (tb + (2 * w) * 64 + lane) * 8)     = lo;
        *(bf16x8*)(wxp + (tb + (2 * w + 1) * 64 + lane) * 8) = hi;
    }
}

// ---------- low-rank scan: 16 WGs x 512 threads ----------
__global__ __launch_bounds__(512, 1) void k_scan_lr(const float* __restrict__ h_in,
                                                    const float* __restrict__ alpha,
                                                    const int* __restrict__ Kp,
                                                    const bf16_t* __restrict__ V2G,
                                                    const bf16_t* __restrict__ Vb,
                                                    const bf16_t* __restrict__ wxp,
                                                    float* __restrict__ out) {
    __shared__ bf16_t S[16 * SSTR];    // s = h_cur + h_prev (single buffer is safe:
    __shared__ bf16_t U[16 * USTR];    //  S read only before barrier A, written after)
    int g = blockIdx.x, tid = threadIdx.x;
    int lane = tid & 63, wv = tid >> 6, quad = lane >> 4, m = lane & 15;
    int colbase = wv * 32 + m;

    // stage2 B-frags: V (64 x 256), this wave's 32 cols, K=64 (kt=0..1)
    bf16x8 Vf[4];
    #pragma unroll
    for (int c = 0; c < 2; ++c)
        #pragma unroll
        for (int kt = 0; kt < 2; ++kt) {
            bf16x8 f;
            #pragma unroll
            for (int j = 0; j < 8; ++j)
                f[j] = Vb[(kt * 32 + quad * 8 + j) * HID + colbase + c * 16];
            Vf[c * 2 + kt] = f;
        }

    // stage1 B-frags (waves 0-3 only): V2G (256 x 64), col-tile wv
    bf16x8 Gf[8];
    int ucol = (wv & 3) * 16 + m;
    if (wv < 4) {
        #pragma unroll
        for (int kt = 0; kt < 8; ++kt) {
            bf16x8 f;
            #pragma unroll
            for (int j = 0; j < 8; ++j)
                f[j] = V2G[(kt * 32 + quad * 8 + j) * 64 + ucol];
            Gf[kt] = f;
        }
    }

    float hp[8], hc[8], sreg[8];
    #pragma unroll
    for (int c = 0; c < 2; ++c)
        #pragma unroll
        for (int r = 0; r < 4; ++r) {
            int e = c * 4 + r;
            int row = quad * 4 + r, col = colbase + c * 16;
            float v = h_in[(g * 16 + row) * HID + col];
            hp[e] = v; hc[e] = v; sreg[e] = 2.0f * v;
            S[row * SSTR + col] = (bf16_t)(2.0f * v);
        }
    float a = alpha[0];
    float one_ma = 1.0f - a;
    int K = Kp[0];
    if (K < 1 || K > 64) K = 1;
    __syncthreads();

    const bf16x8* wptr = (const bf16x8*)wxp;
    int wbase = g * 512 + tid;
    bf16x8 wx = wptr[wbase];

    for (int t = 0; t < SEQ; ++t) {
        int tn = (t + 1 < SEQ) ? t + 1 : t;
        bf16x8 wxn = wptr[tn * (16 * 512) + wbase];   // prefetch next step

        for (int k = 0; k < K; ++k) {
            // ---- stage1: u = s @ V2G (waves 0-3) ----
            if (wv < 4) {
                f32x4 a1 = (f32x4){0.f, 0.f, 0.f, 0.f};
                const bf16_t* sb = &S[m * SSTR];
                #pragma unroll
                for (int kt = 0; kt < 8; ++kt) {
                    bf16x8 af = *(const bf16x8*)(sb + kt * 32 + quad * 8);
                    a1 = __builtin_amdgcn_mfma_f32_16x16x32_bf16(af, Gf[kt], a1, 0, 0, 0);
                }
                #pragma unroll
                for (int r = 0; r < 4; ++r)
                    U[(quad * 4 + r) * USTR + ucol] = (bf16_t)a1[r];
            }
            __syncthreads();   // barrier A: u ready

            // ---- stage2: pre = s + u@V + wx ; epilogue ----
            f32x4 acc[2];
            #pragma unroll
            for (int c = 0; c < 2; ++c)
                #pragma unroll
                for (int r = 0; r < 4; ++r) acc[c][r] = (float)wx[c * 4 + r];
            const bf16_t* ub = &U[m * USTR];
            bf16x8 u0 = *(const bf16x8*)(ub + quad * 8);
            bf16x8 u1 = *(const bf16x8*)(ub + 32 + quad * 8);
            #pragma unroll
            for (int c = 0; c < 2; ++c) {
                acc[c] = __builtin_amdgcn_mfma_f32_16x16x32_bf16(u0, Vf[c * 2 + 0], acc[c], 0, 0, 0);
                acc[c] = __builtin_amdgcn_mfma_f32_16x16x32_bf16(u1, Vf[c * 2 + 1], acc[c], 0, 0, 0);
            }
            bool last = (k == K - 1);
            #pragma unroll
            for (int c = 0; c < 2; ++c) {
                int col = colbase + c * 16;
                #pragma unroll
                for (int r = 0; r < 4; ++r) {
                    int e = c * 4 + r;
                    int row = quad * 4 + r;
                    float pre = acc[c][r] + sreg[e];      // identity part, exact f32
                    float T = fast_tanh(pre);
                    float hn = a * (T - hp[e]) + one_ma * hc[e];
                    float sn;
                    if (last) { hp[e] = hn; hc[e] = hn; sn = 2.0f * hn; }
                    else      { hc[e] = hn; sn = hn + hp[e]; }
                    sreg[e] = sn;
                    S[row * SSTR + col] = (bf16_t)sn;
                }
            }
            __syncthreads();   // barrier B: s' ready
        }
        wx = wxn;
    }

    #pragma unroll
    for (int c = 0; c < 2; ++c)
        #pragma unroll
        for (int r = 0; r < 4; ++r) {
            int row = quad * 4 + r, col = colbase + c * 16;
            out[(g * 16 + row) * HID + col] = hp[c * 4 + r];
        }
}

// ---------- fallback (ws too small): R4's proven fused scan ----------
__global__ __launch_bounds__(256, 1) void k_scan_fused(const float* __restrict__ h_in,
                                                 const float* __restrict__ alpha,
                                                 const int* __restrict__ Kp,
                                                 const bf16_t* __restrict__ E,
                                                 const bf16_t* __restrict__ WP,
                                                 const float* __restrict__ bP,
                                                 const float* __restrict__ x,
                                                 float* __restrict__ out) {
    __shared__ bf16_t S[2][16 * SSTR];
    int g = blockIdx.x;
    int tid = threadIdx.x;
    int lane = tid & 63, w = tid >> 6, quad = lane >> 4, m = lane & 15;
    int colbase = w * 64 + m;
    bf16x8 Ef[32];
    bf16x8 Wf[16];
    float bPv[4];
    #pragma unroll
    for (int c = 0; c < 4; ++c) {
        int col = colbase + c * 16;
        bPv[c] = bP[col];
        #pragma unroll
        for (int kt = 0; kt < 8; ++kt) {
            bf16x8 f;
            #pragma unroll
            for (int j = 0; j < 8; ++j)
                f[j] = E[(kt * 32 + quad * 8 + j) * HID + col];
            Ef[c * 8 + kt] = f;
        }
        #pragma unroll
        for (int kt = 0; kt < 4; ++kt) {
            bf16x8 f;
            #pragma unroll
            for (int j = 0; j < 8; ++j)
                f[j] = WP[(kt * 32 + quad * 8 + j) * HID + col];
            Wf[c * 4 + kt] = f;
        }
    }
    float hp[16], hc[16], sreg[16];
    #pragma unroll
    for (int c = 0; c < 4; ++c)
        #pragma unroll
        for (int r = 0; r < 4; ++r) {
            int e = c * 4 + r;
            int row = quad * 4 + r, col = colbase + c * 16;
            float v = h_in[(g * 16 + row) * HID + col];
            hp[e] = v; hc[e] = v; sreg[e] = 2.0f * v;
            S[0][row * SSTR + col] = (bf16_t)(2.0f * v);
        }
    float a = alpha[0];
    float one_ma = 1.0f - a;
    int K = Kp[0];
    if (K < 1 || K > 64) K = 1;
    __syncthreads();
    const float* xrow = x + ((g * 16 + m) * NF + quad * 8);
    bf16x8 xf[4];
    #pragma unroll
    for (int kt = 0; kt < 4; ++kt) {
        f32x4 xa = *(const f32x4*)(xrow + kt * 32);
        f32x4 xb = *(const f32x4*)(xrow + kt * 32 + 4);
        bf16x8 f;
        #pragma unroll
        for (int j = 0; j < 4; ++j) { f[j] = (bf16_t)xa[j]; f[4 + j] = (bf16_t)xb[j]; }
        xf[kt] = f;
    }
    int p = 0;
    for (int t = 0; t < SEQ; ++t) {
        int tn = (t + 1 < SEQ) ? t + 1 : t;
        const float* xn = xrow + tn * (256 * NF);
        bf16x8 xnf[4];
        #pragma unroll
        for (int kt = 0; kt < 4; ++kt) {
            f32x4 xa = *(const f32x4*)(xn + kt * 32);
            f32x4 xb = *(const f32x4*)(xn + kt * 32 + 4);
            bf16x8 f;
            #pragma unroll
            for (int j = 0; j < 4; ++j) { f[j] = (bf16_t)xa[j]; f[4 + j] = (bf16_t)xb[j]; }
            xnf[kt] = f;
        }
        f32x4 wxacc[4];
        #pragma unroll
        for (int c = 0; c < 4; ++c) wxacc[c] = (f32x4){bPv[c], bPv[c], bPv[c], bPv[c]};
        #pragma unroll
        for (int kt = 0; kt < 4; ++kt)
            #pragma unroll
            for (int c = 0; c < 4; ++c)
                wxacc[c] = __builtin_amdgcn_mfma_f32_16x16x32_bf16(xf[kt], Wf[c * 4 + kt], wxacc[c], 0, 0, 0);
        for (int k = 0; k < K; ++k) {
            f32x4 acc[4];
            #pragma unroll
            for (int c = 0; c < 4; ++c) acc[c] = wxacc[c];
            const bf16_t* sbase = &S[p][m * SSTR];
            #pragma unroll
            for (int kt = 0; kt < 8; ++kt) {
                bf16x8 af = *(const bf16x8*)(sbase + kt * 32 + quad * 8);
                #pragma unroll
                for (int c = 0; c < 4; ++c)
                    acc[c] = __builtin_amdgcn_mfma_f32_16x16x32_bf16(af, Ef[c * 8 + kt], acc[c], 0, 0, 0);
            }
            bool last = (k == K - 1);
            #pragma unroll
            for (int c = 0; c < 4; ++c) {
                int col = colbase + c * 16;
                #pragma unroll
                for (int r = 0; r < 4; ++r) {
                    int e = c * 4 + r;
                    int row = quad * 4 + r;
                    float pre = acc[c][r] + sreg[e];
                    float T = fast_tanh(pre);
                    float hn = a * (T - hp[e]) + one_ma * hc[e];
                    float sn;
                    if (last) { hp[e] = hn; hc[e] = hn; sn = 2.0f * hn; }
                    else      { hc[e] = hn; sn = hn + hp[e]; }
                    sreg[e] = sn;
                    S[p ^ 1][row * SSTR + col] = (bf16_t)sn;
                }
            }
            p ^= 1;
            __syncthreads();
        }
        #pragma unroll
        for (int kt = 0; kt < 4; ++kt) xf[kt] = xnf[kt];
    }
    #pragma unroll
    for (int c = 0; c < 4; ++c)
        #pragma unroll
        for (int r = 0; r < 4; ++r) {
            int row = quad * 4 + r, col = colbase + c * 16;
            out[(g * 16 + row) * HID + col] = hp[c * 4 + r];
        }
}

extern "C" void kernel_launch(void* const* d_in, const int* in_sizes, int n_in,
                              void* d_out, int out_size, void* d_ws, size_t ws_size,
                              hipStream_t stream) {
    const float* x     = (const float*)d_in[0];
    const float* h     = (const float*)d_in[1];
    const float* W     = (const float*)d_in[2];
    const float* b     = (const float*)d_in[3];
    const float* V     = (const float*)d_in[4];
    const float* V2    = (const float*)d_in[5];
    const float* alpha = (const float*)d_in[6];
    const int*   Kp    = (const int*)d_in[7];

    char* ws = (char*)d_ws;
    float*  P    = (float*)ws;                     // 256 KB
    float*  G    = (float*)(ws + (256u << 10));    // 16 KB
    bf16_t* V2G  = (bf16_t*)(ws + (272u << 10));   // 32 KB
    bf16_t* Vb   = (bf16_t*)(ws + (304u << 10));   // 32 KB
    bf16_t* WP   = (bf16_t*)(ws + (336u << 10));   // 64 KB
    float*  bP   = (float*)(ws + (400u << 10));    // 1 KB
    bf16_t* E    = (bf16_t*)(ws + (401u << 10));   // 128 KB (fallback only)
    bf16_t* wxp  = (bf16_t*)(ws + (640u << 10));   // 128 MB
    size_t need = (640u << 10) + (size_t)SEQ * 16 * 512 * 8 * sizeof(bf16_t);

    hipLaunchKernelGGL(k_P,  dim3(256), dim3(256), 0, stream, V2, V, P);
    hipLaunchKernelGGL(k_WP, dim3(129), dim3(256), 0, stream, W, b, P, WP, bP);
    if (ws_size >= need) {
        hipLaunchKernelGGL(k_G,    dim3(64),   dim3(64),  0, stream, V, V2, G);
        hipLaunchKernelGGL(k_V2G,  dim3(256),  dim3(64),  0, stream, V2, G, V2G);
        hipLaunchKernelGGL(k_Vb,   dim3(64),   dim3(256), 0, stream, V, Vb);
        hipLaunchKernelGGL(k_wxp,  dim3(2048), dim3(256), 0, stream, x, WP, bP, wxp);
        hipLaunchKernelGGL(k_scan_lr, dim3(16), dim3(512), 0, stream, h, alpha, Kp, V2G, Vb, wxp, (float*)d_out);
    } else {
        hipLaunchKernelGGL(k_E, dim3(256), dim3(256), 0, stream, P, E);
        hipLaunchKernelGGL(k_scan_fused, dim3(16), dim3(256), 0, stream, h, alpha, Kp, E, WP, bP, x, (float*)d_out);
    }
}